// Round 15
// baseline (237.364 us; speedup 1.0000x reference)
//
#include <hip/hip_runtime.h>

#define DIM_ 768
#define MID_ 96

typedef float f32x4 __attribute__((ext_vector_type(4)));
typedef __bf16 bf16x8 __attribute__((ext_vector_type(8)));
typedef __bf16 bf16x4 __attribute__((ext_vector_type(4)));

// ---------------------------------------------------------------------------
// K_prep: fused weight prep.
// Blocks [0,48): fold LN scale into down/down1 weights; sw/cb constants.
// Blocks [48,141): bf16-cast up_w, pw_w; zero gvec partials.
// ---------------------------------------------------------------------------
__global__ __launch_bounds__(256) void k_prep(
        const float* __restrict__ dw, const float* __restrict__ db,
        const float* __restrict__ lnw0, const float* __restrict__ lnb0,
        const float* __restrict__ d1w, const float* __restrict__ d1b,
        const float* __restrict__ lnw1, const float* __restrict__ lnb1,
        __bf16* __restrict__ wln0, __bf16* __restrict__ wln1,
        float* __restrict__ swcb,
        const float* __restrict__ uw, const float* __restrict__ pw,
        __bf16* __restrict__ bup, __bf16* __restrict__ bpw,
        float* __restrict__ part) {
    if (blockIdx.x >= 48) {
        const int t = (blockIdx.x - 48) * 256 + threadIdx.x;
        const float* src;
        __bf16* dst;
        int i;
        if (t < 18432)      { src = uw; dst = bup; i = t; }
        else if (t < 23040) { src = pw; dst = bpw; i = t - 18432; }
        else if (t < 23808) { part[t - 23040] = 0.f; return; }
        else return;
        float4 v = reinterpret_cast<const float4*>(src)[i];
        bf16x4 o;
        o[0] = (__bf16)v.x; o[1] = (__bf16)v.y;
        o[2] = (__bf16)v.z; o[3] = (__bf16)v.w;
        *reinterpret_cast<bf16x4*>(dst + (size_t)i * 4) = o;
        return;
    }
    const int wid = blockIdx.x * 4 + (threadIdx.x >> 6);
    const int lane = threadIdx.x & 63;
    const int mat = wid >= 96;
    const int n = mat ? wid - 96 : wid;
    const float* W   = mat ? d1w : dw;
    const float* bia = mat ? d1b : db;
    const float* lw  = mat ? lnw1 : lnw0;
    const float* lb  = mat ? lnb1 : lnb0;
    __bf16* dst = mat ? wln1 : wln0;
    float sacc = 0.f, cacc = 0.f;
#pragma unroll
    for (int j = 0; j < 12; ++j) {
        const int k = j * 64 + lane;
        const float w = W[(size_t)n * DIM_ + k];
        const float val = w * lw[k];
        const __bf16 bv = (__bf16)val;
        dst[(size_t)n * DIM_ + k] = bv;
        sacc += (float)bv;
        cacc += lb[k] * w;
    }
#pragma unroll
    for (int m = 1; m < 64; m <<= 1) {
        sacc += __shfl_xor(sacc, m, 64);
        cacc += __shfl_xor(cacc, m, 64);
    }
    if (lane == 0) {
        swcb[mat * 192 + n] = sacc;               // sw
        swcb[mat * 192 + 96 + n] = cacc + bia[n]; // cb
    }
}

// ---------------------------------------------------------------------------
// K_downf v6: r8 structure with N-SPLIT for 2x wave concurrency.
// Each block stages only its 48-col half of W (72 KB LDS) -> 2 blocks/CU
// = 8 waves/SIMD (r8's 147 KB forced 1 block/CU = 4 waves/SIMD, and every
// counter showed pure latency-bound idleness at fixed in-flight bytes).
// Grid 512: bit0 tensor, bit1 N-half, rest -> 256-row chunk. x rows read
// twice (second read L2/L3-hits; HBM traffic unchanged). Stats per-wave
// (full K read anyway); gvec columns disjoint across nh (no double count).
// ---------------------------------------------------------------------------
__global__ __launch_bounds__(1024)
__attribute__((amdgpu_waves_per_eu(8, 8)))
void k_downf(
        const float* __restrict__ xsrc, const float* __restrict__ tsrc,
        const __bf16* __restrict__ wln0, const __bf16* __restrict__ wln1,
        const float* __restrict__ swcb, __bf16* __restrict__ xemb,
        __bf16* __restrict__ temb, float* __restrict__ part) {
    extern __shared__ __bf16 Wp[];   // 48*768 = 36864 elems = 73728 B
    const int t = threadIdx.x;
    const int half = blockIdx.x & 1;        // 0: x, 1: t
    const int nh = (blockIdx.x >> 1) & 1;   // N-half: cols [nh*48, +48)
    const int mb = blockIdx.x >> 2;         // 0..127
    const float* src = half ? tsrc : xsrc;
    const __bf16* wln = half ? wln1 : wln0;
    const float* sc = swcb + half * 192;
    __bf16* outb = half ? temb : xemb;

    // stage W half in fragment order: idx = (kt*3 + f)*64 + lane  (4608 items)
#pragma unroll
    for (int i = 0; i < 5; ++i) {
        const int idx = t + i * 1024;
        if (idx < 4608) {
            const int ls = idx & 63;
            const int rem = idx >> 6;              // kt*3 + f
            const int kt = rem / 3;
            const int f = rem - kt * 3;
            const int row = nh * 48 + f * 16 + (ls & 15);
            const int col = kt * 32 + (ls >> 4) * 8;
            *reinterpret_cast<bf16x8*>(Wp + (size_t)idx * 8) =
                *reinterpret_cast<const bf16x8*>(wln + (size_t)row * DIM_ + col);
        }
    }
    __syncthreads();

    const int lane = t & 63, wave = t >> 6;   // 16 waves, 16 rows each
    const int l15 = lane & 15, l4 = lane >> 4;
    const int row = mb * 256 + wave * 16 + l15;
    const float* rp = src + (size_t)row * DIM_ + l4 * 8;

    float s = 0.f, sq = 0.f;
    f32x4 acc[3] = {};

    auto cvt = [&](const float4& v0, const float4& v1) -> bf16x8 {
        s += v0.x + v0.y + v0.z + v0.w + v1.x + v1.y + v1.z + v1.w;
        sq += v0.x * v0.x + v0.y * v0.y + v0.z * v0.z + v0.w * v0.w +
              v1.x * v1.x + v1.y * v1.y + v1.z * v1.z + v1.w * v1.w;
        bf16x8 a;
        a[0] = (__bf16)v0.x; a[1] = (__bf16)v0.y;
        a[2] = (__bf16)v0.z; a[3] = (__bf16)v0.w;
        a[4] = (__bf16)v1.x; a[5] = (__bf16)v1.y;
        a[6] = (__bf16)v1.z; a[7] = (__bf16)v1.w;
        return a;
    };
    auto consume = [&](const bf16x8& a, int kt) {
        const __bf16* bp = Wp + ((size_t)(kt * 3) * 64 + lane) * 8;
#pragma unroll
        for (int f = 0; f < 3; ++f) {
            bf16x8 b = *reinterpret_cast<const bf16x8*>(bp + (size_t)f * 64 * 8);
            acc[f] = __builtin_amdgcn_mfma_f32_16x16x32_bf16(a, b, acc[f], 0, 0, 0);
        }
    };

    float4 w0a = *reinterpret_cast<const float4*>(rp + 0);
    float4 w0b = *reinterpret_cast<const float4*>(rp + 4);
    float4 w1a = *reinterpret_cast<const float4*>(rp + 32);
    float4 w1b = *reinterpret_cast<const float4*>(rp + 36);
    bf16x8 a0 = cvt(w0a, w0b);
    bf16x8 a1 = cvt(w1a, w1b);
    w0a = *reinterpret_cast<const float4*>(rp + 64);
    w0b = *reinterpret_cast<const float4*>(rp + 68);
    w1a = *reinterpret_cast<const float4*>(rp + 96);
    w1b = *reinterpret_cast<const float4*>(rp + 100);
#pragma unroll
    for (int kt = 0; kt < 24; kt += 2) {
        consume(a0, kt);
        if (kt + 2 < 24) {
            a0 = cvt(w0a, w0b);
            if (kt + 4 < 24) {
                w0a = *reinterpret_cast<const float4*>(rp + (kt + 4) * 32);
                w0b = *reinterpret_cast<const float4*>(rp + (kt + 4) * 32 + 4);
            }
        }
        consume(a1, kt + 1);
        if (kt + 3 < 24) {
            a1 = cvt(w1a, w1b);
            if (kt + 5 < 24) {
                w1a = *reinterpret_cast<const float4*>(rp + (kt + 5) * 32);
                w1b = *reinterpret_cast<const float4*>(rp + (kt + 5) * 32 + 4);
            }
        }
    }

    s += __shfl_xor(s, 16, 64); sq += __shfl_xor(sq, 16, 64);
    s += __shfl_xor(s, 32, 64); sq += __shfl_xor(sq, 32, 64);
    const float mean = s * (1.f / 768.f);
    const float rstd = rsqrtf(sq * (1.f / 768.f) - mean * mean + 1e-6f);
    const float mur = mean * rstd;
    float rstd_r[4], mur_r[4];
#pragma unroll
    for (int rr = 0; rr < 4; ++rr) {
        rstd_r[rr] = __shfl(rstd, l4 * 4 + rr, 64);
        mur_r[rr]  = __shfl(mur,  l4 * 4 + rr, 64);
    }

    const int orow0 = mb * 256 + wave * 16 + l4 * 4;
    const int batch = mb >> 4;     // 16 chunks per image
#pragma unroll
    for (int f = 0; f < 3; ++f) {
        const int col = nh * 48 + f * 16 + l15;
        const float swc = sc[col];
        const float cbc = sc[96 + col];
        float colsum = 0.f;
#pragma unroll
        for (int rr = 0; rr < 4; ++rr) {
            const float val = acc[f][rr] * rstd_r[rr] - mur_r[rr] * swc + cbc;
            outb[(size_t)(orow0 + rr) * MID_ + col] = (__bf16)val;
            colsum += val;
        }
        if (half == 0) {
            colsum += __shfl_xor(colsum, 16, 64);
            colsum += __shfl_xor(colsum, 32, 64);
            if (l4 == 0) atomicAdd(&part[batch * MID_ + col], colsum);
        }
    }
}

// ---------------------------------------------------------------------------
// K_mlp: gvec mean from part, MLP (96->24 relu ->4), softmax -> wts [8,4]
// ---------------------------------------------------------------------------
__global__ __launch_bounds__(128) void k_mlp(const float* __restrict__ part,
        const float* __restrict__ m1w, const float* __restrict__ m1b,
        const float* __restrict__ m2w, const float* __restrict__ m2b,
        float* __restrict__ wts) {
    const int b = blockIdx.x, t = threadIdx.x;
    __shared__ float gv[96];
    __shared__ float hid[24];
    __shared__ float lg[4];
    if (t < 96) gv[t] = part[b * MID_ + t] * (1.f / 4096.f);
    __syncthreads();
    if (t < 24) {
        float s = m1b[t];
        for (int c = 0; c < 96; ++c) s += gv[c] * m1w[t * 96 + c];
        hid[t] = fmaxf(s, 0.f);
    }
    __syncthreads();
    if (t < 4) {
        float s = m2b[t];
        for (int j = 0; j < 24; ++j) s += hid[j] * m2w[t * 24 + j];
        lg[t] = s;
    }
    __syncthreads();
    if (t < 4) {
        const float m = fmaxf(fmaxf(lg[0], lg[1]), fmaxf(lg[2], lg[3]));
        const float e = __expf(lg[t] - m);
        const float sum = __expf(lg[0] - m) + __expf(lg[1] - m) +
                          __expf(lg[2] - m) + __expf(lg[3] - m);
        wts[b * 4 + t] = e / sum;
    }
}

// ---------------------------------------------------------------------------
// K_dyn: precompute dyn kernels once per batch: dyng[b][pq][c].
// ---------------------------------------------------------------------------
__global__ __launch_bounds__(256) void k_dyn(const float* __restrict__ wts,
        const float* __restrict__ basis, float* __restrict__ dyng) {
    const int idx = blockIdx.x * 256 + threadIdx.x;
    if (idx >= 8 * 4704) return;
    const int b = idx / 4704;
    const int rem = idx - b * 4704;     // pq*96 + c
    const int pq = rem / 96;
    const int c = rem - pq * 96;
    const size_t off = (size_t)c * 49 + pq;
    dyng[idx] = wts[b * 4 + 0] * basis[off] +
                wts[b * 4 + 1] * basis[off + 4704] +
                wts[b * 4 + 2] * basis[off + 9408] +
                wts[b * 4 + 3] * basis[off + 14112];
}

// ---------------------------------------------------------------------------
// K_dwconv: depthwise 3x3 conv (zero pad) + SiLU. temb bf16 -> y bf16.
// ---------------------------------------------------------------------------
__global__ __launch_bounds__(256) void k_dwconv(const __bf16* __restrict__ temb,
        const float* __restrict__ dww, const float* __restrict__ dwb,
        __bf16* __restrict__ y) {
    __shared__ float wls[96 * 9];
    __shared__ float bls[96];
    const int t = threadIdx.x;
    for (int i = t; i < 96 * 9; i += 256) wls[i] = dww[i];
    if (t < 96) bls[t] = dwb[t];
    __syncthreads();
    const int b = blockIdx.x >> 6, h = blockIdx.x & 63;
    const __bf16* base = temb + (size_t)b * 4096 * MID_;
    for (int o = t; o < 64 * 96; o += 256) {
        const int w = o / 96;
        const int c = o - w * 96;
        float acc = bls[c];
#pragma unroll
        for (int dh = 0; dh < 3; ++dh) {
            const int hh = h + dh - 1;
            if (hh < 0 || hh > 63) continue;
#pragma unroll
            for (int dw = 0; dw < 3; ++dw) {
                const int ww = w + dw - 1;
                if (ww < 0 || ww > 63) continue;
                acc += (float)base[((size_t)hh * 64 + ww) * MID_ + c] *
                       wls[c * 9 + dh * 3 + dw];
            }
        }
        y[((size_t)(b * 64 + h) * 64 + w) * MID_ + c] =
            (__bf16)(acc / (1.f + __expf(-acc)));
    }
}

// ---------------------------------------------------------------------------
// K_style: style GEMM (y @ pw_w^T + pw_b) fused with modulation:
// common = x_emb * (1 + gamma) + beta -> bf16. K=96 fully staged, 1 barrier.
// ---------------------------------------------------------------------------
__global__ __launch_bounds__(256) void k_style(const __bf16* __restrict__ y,
        const __bf16* __restrict__ wpw, const float* __restrict__ pwb,
        const __bf16* __restrict__ xemb, __bf16* __restrict__ common) {
    __shared__ bf16x8 As[64][13];
    __shared__ bf16x8 Bs[192][13];
    const int t = threadIdx.x;
    const int row0 = blockIdx.x * 64;
    for (int idx = t; idx < 768; idx += 256) {
        const int rr = idx / 12, q = idx - rr * 12;
        As[rr][q] = *reinterpret_cast<const bf16x8*>(
            y + (size_t)(row0 + rr) * MID_ + q * 8);
    }
    for (int idx = t; idx < 2304; idx += 256) {
        const int rr = idx / 12, q = idx - rr * 12;
        Bs[rr][q] = *reinterpret_cast<const bf16x8*>(
            wpw + (size_t)rr * MID_ + q * 8);
    }
    __syncthreads();
    const int lane = t & 63, wave = t >> 6;
    const int l15 = lane & 15, l4 = lane >> 4;
    f32x4 acc[12] = {};
    const int ar = wave * 16 + l15;
#pragma unroll
    for (int kt = 0; kt < 3; ++kt) {
        bf16x8 a = As[ar][kt * 4 + l4];
#pragma unroll
        for (int f = 0; f < 12; ++f) {
            bf16x8 b = Bs[f * 16 + l15][kt * 4 + l4];
            acc[f] = __builtin_amdgcn_mfma_f32_16x16x32_bf16(a, b, acc[f], 0, 0, 0);
        }
    }
    const int orow = row0 + wave * 16 + l4 * 4;
#pragma unroll
    for (int f = 0; f < 6; ++f) {
        const int col = f * 16 + l15;
        const float pbg = pwb[col];
        const float pbb = pwb[col + 96];
#pragma unroll
        for (int rr = 0; rr < 4; ++rr) {
            const float g = acc[f][rr] + pbg;
            const float bt = acc[f + 6][rr] + pbb;
            const float xe = (float)xemb[(size_t)(orow + rr) * MID_ + col];
            common[(size_t)(orow + rr) * MID_ + col] = (__bf16)(xe * (1.f + g) + bt);
        }
    }
}

// ---------------------------------------------------------------------------
// K_circ v2: circular 7x7 conv. dyn from dyng; guard-free sliding window.
// ---------------------------------------------------------------------------
__global__ __launch_bounds__(192) void k_circ(const __bf16* __restrict__ common,
        const float* __restrict__ dyng, __bf16* __restrict__ outc) {
    __shared__ float dyn[49 * 96];
    const int t = threadIdx.x;
    const int b = blockIdx.x >> 7;
    const int h = (blockIdx.x >> 1) & 63;
    const int wslice = blockIdx.x & 1;
    const float* dsrc = dyng + (size_t)b * 4704;
    for (int idx = t; idx < 4704; idx += 192) dyn[idx] = dsrc[idx];
    __syncthreads();
    const int c = t % 96;
    const int wg = t / 96;
    const int wbase = wslice * 32 + wg * 16;
    const __bf16* cb = common + (size_t)b * 4096 * MID_ + c;
    float acc[16] = {};
#pragma unroll 1
    for (int p = 0; p < 7; ++p) {
        const int hh = (h + 3 - p) & 63;
        const __bf16* rp = cb + (size_t)hh * 64 * MID_;
        float dynr[7];
#pragma unroll
        for (int q = 0; q < 7; ++q) dynr[q] = dyn[(p * 7 + q) * 96 + c];
        float win[22];
#pragma unroll
        for (int i = 0; i < 22; ++i)
            win[i] = (float)rp[(size_t)((wbase - 3 + i) & 63) * MID_];
#pragma unroll
        for (int li = 0; li < 16; ++li) {
            float a = acc[li];
#pragma unroll
            for (int q = 0; q < 7; ++q) a += dynr[q] * win[li + 6 - q];
            acc[li] = a;
        }
    }
    const size_t obase = ((size_t)(b * 64 + h) * 64 + wbase) * MID_ + c;
#pragma unroll
    for (int li = 0; li < 16; ++li)
        outc[obase + (size_t)li * MID_] = (__bf16)acc[li];
}

// ---------------------------------------------------------------------------
// K_up: out = a_in[32768,96] @ up_w_bf16[768,96]^T + up_b + x  (fp32 out)
// ---------------------------------------------------------------------------
__global__ __launch_bounds__(256) void k_up(const __bf16* __restrict__ a_in,
        const __bf16* __restrict__ wbf, const float* __restrict__ upb,
        const float* __restrict__ x, float* __restrict__ out) {
    __shared__ bf16x8 As[128][13];
    __shared__ bf16x8 Ws[96][13];
    const int t = threadIdx.x;
    const int mt = blockIdx.x >> 3, nt = blockIdx.x & 7;
    const int row0 = mt * 128, col0 = nt * 96;
    for (int idx = t; idx < 1536; idx += 256) {
        const int rr = idx / 12, q = idx - rr * 12;
        As[rr][q] = *reinterpret_cast<const bf16x8*>(
            a_in + (size_t)(row0 + rr) * MID_ + q * 8);
    }
    for (int idx = t; idx < 1152; idx += 256) {
        const int rr = idx / 12, q = idx - rr * 12;
        Ws[rr][q] = *reinterpret_cast<const bf16x8*>(
            wbf + (size_t)(col0 + rr) * MID_ + q * 8);
    }
    __syncthreads();
    const int lane = t & 63, wave = t >> 6;
    const int l15 = lane & 15, l4 = lane >> 4;
    f32x4 acc[2][6] = {};
#pragma unroll
    for (int kt = 0; kt < 3; ++kt) {
        bf16x8 a0 = As[wave * 32 + l15][kt * 4 + l4];
        bf16x8 a1 = As[wave * 32 + 16 + l15][kt * 4 + l4];
#pragma unroll
        for (int f = 0; f < 6; ++f) {
            bf16x8 b = Ws[f * 16 + l15][kt * 4 + l4];
            acc[0][f] = __builtin_amdgcn_mfma_f32_16x16x32_bf16(a0, b, acc[0][f], 0, 0, 0);
            acc[1][f] = __builtin_amdgcn_mfma_f32_16x16x32_bf16(a1, b, acc[1][f], 0, 0, 0);
        }
    }
#pragma unroll
    for (int mr = 0; mr < 2; ++mr) {
        const int orow = row0 + wave * 32 + mr * 16 + l4 * 4;
#pragma unroll
        for (int f = 0; f < 6; ++f) {
            const int col = col0 + f * 16 + l15;
            const float ub = upb[col];
#pragma unroll
            for (int rr = 0; rr < 4; ++rr) {
                const size_t idx = (size_t)(orow + rr) * DIM_ + col;
                out[idx] = acc[mr][f][rr] + ub + x[idx];
            }
        }
    }
}

// ---------------------------------------------------------------------------
extern "C" void kernel_launch(void* const* d_in, const int* in_sizes, int n_in,
                              void* d_out, int out_size, void* d_ws, size_t ws_size,
                              hipStream_t stream) {
    (void)in_sizes; (void)n_in; (void)out_size; (void)ws_size;
    const float* x      = (const float*)d_in[0];
    const float* tt     = (const float*)d_in[1];
    const float* ln_w   = (const float*)d_in[2];
    const float* ln_b   = (const float*)d_in[3];
    const float* down_w = (const float*)d_in[4];
    const float* down_b = (const float*)d_in[5];
    const float* ln1_w  = (const float*)d_in[6];
    const float* ln1_b  = (const float*)d_in[7];
    const float* down1_w= (const float*)d_in[8];
    const float* down1_b= (const float*)d_in[9];
    const float* dw_w   = (const float*)d_in[10];
    const float* dw_b   = (const float*)d_in[11];
    const float* pw_w   = (const float*)d_in[12];
    const float* pw_b   = (const float*)d_in[13];
    const float* m1w    = (const float*)d_in[14];
    const float* m1b    = (const float*)d_in[15];
    const float* m2w    = (const float*)d_in[16];
    const float* m2b    = (const float*)d_in[17];
    const float* basis  = (const float*)d_in[18];
    const float* up_w   = (const float*)d_in[19];
    const float* up_b   = (const float*)d_in[20];
    float* out = (float*)d_out;
    char* ws = (char*)d_ws;

    // workspace layout (bytes)
    __bf16* wln_down  = (__bf16*)(ws + 0);          // 96*768*2  = 147456
    __bf16* wln_down1 = (__bf16*)(ws + 147456);
    __bf16* wbf_up    = (__bf16*)(ws + 294912);     // 768*96*2
    __bf16* wbf_pw    = (__bf16*)(ws + 442368);     // 192*96*2 = 36864
    float*  part      = (float*)(ws + 479232);      // 8*96*4 = 3072
    float*  wts       = (float*)(ws + 482304);      // 32*4
    float*  swcb      = (float*)(ws + 482560);      // 2*192*4 = 1536
    __bf16* x_emb     = (__bf16*)(ws + 524288);     // 32768*96*2 = 6291456
    __bf16* t_emb     = (__bf16*)(ws + 6815744);
    __bf16* ybuf      = (__bf16*)(ws + 13107200);
    __bf16* common    = (__bf16*)(ws + 19398656);
    __bf16* convout   = (__bf16*)(ws + 25690112);
    float*  dyng      = (float*)(ws + 31981568);    // 8*49*96*4 = 150528

    // opt-in to >64KB dynamic LDS for k_downf (not a stream op; capture-safe)
    (void)hipFuncSetAttribute((const void*)k_downf,
                              hipFuncAttributeMaxDynamicSharedMemorySize, 73728);

    k_prep<<<141, 256, 0, stream>>>(down_w, down_b, ln_w, ln_b,
                                    down1_w, down1_b, ln1_w, ln1_b,
                                    wln_down, wln_down1, swcb,
                                    up_w, pw_w, wbf_up, wbf_pw, part);
    k_downf<<<512, 1024, 73728, stream>>>(x, tt, wln_down, wln_down1, swcb,
                                          x_emb, t_emb, part);
    k_mlp<<<8, 128, 0, stream>>>(part, m1w, m1b, m2w, m2b, wts);
    k_dyn<<<147, 256, 0, stream>>>(wts, basis, dyng);
    k_dwconv<<<512, 256, 0, stream>>>(t_emb, dw_w, dw_b, ybuf);
    k_style<<<512, 256, 0, stream>>>(ybuf, wbf_pw, pw_b, x_emb, common);
    k_circ<<<1024, 192, 0, stream>>>(common, dyng, convout);
    k_up<<<2048, 256, 0, stream>>>(convout, wbf_up, up_b, x, out);
}

// Round 16
// 203.183 us; speedup vs baseline: 1.1682x; 1.1682x over previous
//
#include <hip/hip_runtime.h>

#define DIM_ 768
#define MID_ 96

typedef float f32x4 __attribute__((ext_vector_type(4)));
typedef __bf16 bf16x8 __attribute__((ext_vector_type(8)));
typedef __bf16 bf16x4 __attribute__((ext_vector_type(4)));

// ---------------------------------------------------------------------------
// K_prep: fused weight prep.
// Blocks [0,48): fold LN scale into down/down1 weights; sw/cb constants.
// Blocks [48,141): bf16-cast up_w, pw_w; zero gvec partials.
// ---------------------------------------------------------------------------
__global__ __launch_bounds__(256) void k_prep(
        const float* __restrict__ dw, const float* __restrict__ db,
        const float* __restrict__ lnw0, const float* __restrict__ lnb0,
        const float* __restrict__ d1w, const float* __restrict__ d1b,
        const float* __restrict__ lnw1, const float* __restrict__ lnb1,
        __bf16* __restrict__ wln0, __bf16* __restrict__ wln1,
        float* __restrict__ swcb,
        const float* __restrict__ uw, const float* __restrict__ pw,
        __bf16* __restrict__ bup, __bf16* __restrict__ bpw,
        float* __restrict__ part) {
    if (blockIdx.x >= 48) {
        const int t = (blockIdx.x - 48) * 256 + threadIdx.x;
        const float* src;
        __bf16* dst;
        int i;
        if (t < 18432)      { src = uw; dst = bup; i = t; }
        else if (t < 23040) { src = pw; dst = bpw; i = t - 18432; }
        else if (t < 23808) { part[t - 23040] = 0.f; return; }
        else return;
        float4 v = reinterpret_cast<const float4*>(src)[i];
        bf16x4 o;
        o[0] = (__bf16)v.x; o[1] = (__bf16)v.y;
        o[2] = (__bf16)v.z; o[3] = (__bf16)v.w;
        *reinterpret_cast<bf16x4*>(dst + (size_t)i * 4) = o;
        return;
    }
    const int wid = blockIdx.x * 4 + (threadIdx.x >> 6);
    const int lane = threadIdx.x & 63;
    const int mat = wid >= 96;
    const int n = mat ? wid - 96 : wid;
    const float* W   = mat ? d1w : dw;
    const float* bia = mat ? d1b : db;
    const float* lw  = mat ? lnw1 : lnw0;
    const float* lb  = mat ? lnb1 : lnb0;
    __bf16* dst = mat ? wln1 : wln0;
    float sacc = 0.f, cacc = 0.f;
#pragma unroll
    for (int j = 0; j < 12; ++j) {
        const int k = j * 64 + lane;
        const float w = W[(size_t)n * DIM_ + k];
        const float val = w * lw[k];
        const __bf16 bv = (__bf16)val;
        dst[(size_t)n * DIM_ + k] = bv;
        sacc += (float)bv;
        cacc += lb[k] * w;
    }
#pragma unroll
    for (int m = 1; m < 64; m <<= 1) {
        sacc += __shfl_xor(sacc, m, 64);
        cacc += __shfl_xor(cacc, m, 64);
    }
    if (lane == 0) {
        swcb[mat * 192 + n] = sacc;               // sw
        swcb[mat * 192 + 96 + n] = cacc + bia[n]; // cb
    }
}

// ---------------------------------------------------------------------------
// K_downf v7: N-split (r15) WITHOUT the waves_per_eu attribute.
// r15 evidence: N-split achieved 71% occupancy / 2.83 TB/s (2.3x r14) but
// waves_per_eu(8,8) forced VGPR=32 -> 83 MB spill writes. This kernel's
// live state (~45-50 VGPR: 3 accs + depth-2 fp32 stage + 2 bf16 frags) FITS
// the default 64-VGPR / 8-waves-per-EU target, so dropping the attribute
// keeps the 2-blocks/CU occupancy and kills the spills.
// Grid 512: bit0 tensor, bit1 N-half, rest -> 256-row chunk. 72 KB LDS.
// ---------------------------------------------------------------------------
__global__ __launch_bounds__(1024)
void k_downf(
        const float* __restrict__ xsrc, const float* __restrict__ tsrc,
        const __bf16* __restrict__ wln0, const __bf16* __restrict__ wln1,
        const float* __restrict__ swcb, __bf16* __restrict__ xemb,
        __bf16* __restrict__ temb, float* __restrict__ part) {
    extern __shared__ __bf16 Wp[];   // 48*768 = 36864 elems = 73728 B
    const int t = threadIdx.x;
    const int half = blockIdx.x & 1;        // 0: x, 1: t
    const int nh = (blockIdx.x >> 1) & 1;   // N-half: cols [nh*48, +48)
    const int mb = blockIdx.x >> 2;         // 0..127
    const float* src = half ? tsrc : xsrc;
    const __bf16* wln = half ? wln1 : wln0;
    const float* sc = swcb + half * 192;
    __bf16* outb = half ? temb : xemb;

    // stage W half in fragment order: idx = (kt*3 + f)*64 + lane  (4608 items)
#pragma unroll
    for (int i = 0; i < 5; ++i) {
        const int idx = t + i * 1024;
        if (idx < 4608) {
            const int ls = idx & 63;
            const int rem = idx >> 6;              // kt*3 + f
            const int kt = rem / 3;
            const int f = rem - kt * 3;
            const int row = nh * 48 + f * 16 + (ls & 15);
            const int col = kt * 32 + (ls >> 4) * 8;
            *reinterpret_cast<bf16x8*>(Wp + (size_t)idx * 8) =
                *reinterpret_cast<const bf16x8*>(wln + (size_t)row * DIM_ + col);
        }
    }
    __syncthreads();

    const int lane = t & 63, wave = t >> 6;   // 16 waves, 16 rows each
    const int l15 = lane & 15, l4 = lane >> 4;
    const int row = mb * 256 + wave * 16 + l15;
    const float* rp = src + (size_t)row * DIM_ + l4 * 8;

    float s = 0.f, sq = 0.f;
    f32x4 acc[3] = {};

    auto cvt = [&](const float4& v0, const float4& v1) -> bf16x8 {
        s += v0.x + v0.y + v0.z + v0.w + v1.x + v1.y + v1.z + v1.w;
        sq += v0.x * v0.x + v0.y * v0.y + v0.z * v0.z + v0.w * v0.w +
              v1.x * v1.x + v1.y * v1.y + v1.z * v1.z + v1.w * v1.w;
        bf16x8 a;
        a[0] = (__bf16)v0.x; a[1] = (__bf16)v0.y;
        a[2] = (__bf16)v0.z; a[3] = (__bf16)v0.w;
        a[4] = (__bf16)v1.x; a[5] = (__bf16)v1.y;
        a[6] = (__bf16)v1.z; a[7] = (__bf16)v1.w;
        return a;
    };
    auto consume = [&](const bf16x8& a, int kt) {
        const __bf16* bp = Wp + ((size_t)(kt * 3) * 64 + lane) * 8;
#pragma unroll
        for (int f = 0; f < 3; ++f) {
            bf16x8 b = *reinterpret_cast<const bf16x8*>(bp + (size_t)f * 64 * 8);
            acc[f] = __builtin_amdgcn_mfma_f32_16x16x32_bf16(a, b, acc[f], 0, 0, 0);
        }
    };

    float4 w0a = *reinterpret_cast<const float4*>(rp + 0);
    float4 w0b = *reinterpret_cast<const float4*>(rp + 4);
    float4 w1a = *reinterpret_cast<const float4*>(rp + 32);
    float4 w1b = *reinterpret_cast<const float4*>(rp + 36);
    bf16x8 a0 = cvt(w0a, w0b);
    bf16x8 a1 = cvt(w1a, w1b);
    w0a = *reinterpret_cast<const float4*>(rp + 64);
    w0b = *reinterpret_cast<const float4*>(rp + 68);
    w1a = *reinterpret_cast<const float4*>(rp + 96);
    w1b = *reinterpret_cast<const float4*>(rp + 100);
#pragma unroll
    for (int kt = 0; kt < 24; kt += 2) {
        consume(a0, kt);
        if (kt + 2 < 24) {
            a0 = cvt(w0a, w0b);
            if (kt + 4 < 24) {
                w0a = *reinterpret_cast<const float4*>(rp + (kt + 4) * 32);
                w0b = *reinterpret_cast<const float4*>(rp + (kt + 4) * 32 + 4);
            }
        }
        consume(a1, kt + 1);
        if (kt + 3 < 24) {
            a1 = cvt(w1a, w1b);
            if (kt + 5 < 24) {
                w1a = *reinterpret_cast<const float4*>(rp + (kt + 5) * 32);
                w1b = *reinterpret_cast<const float4*>(rp + (kt + 5) * 32 + 4);
            }
        }
    }

    s += __shfl_xor(s, 16, 64); sq += __shfl_xor(sq, 16, 64);
    s += __shfl_xor(s, 32, 64); sq += __shfl_xor(sq, 32, 64);
    const float mean = s * (1.f / 768.f);
    const float rstd = rsqrtf(sq * (1.f / 768.f) - mean * mean + 1e-6f);
    const float mur = mean * rstd;
    float rstd_r[4], mur_r[4];
#pragma unroll
    for (int rr = 0; rr < 4; ++rr) {
        rstd_r[rr] = __shfl(rstd, l4 * 4 + rr, 64);
        mur_r[rr]  = __shfl(mur,  l4 * 4 + rr, 64);
    }

    const int orow0 = mb * 256 + wave * 16 + l4 * 4;
    const int batch = mb >> 4;     // 16 chunks per image
#pragma unroll
    for (int f = 0; f < 3; ++f) {
        const int col = nh * 48 + f * 16 + l15;
        const float swc = sc[col];
        const float cbc = sc[96 + col];
        float colsum = 0.f;
#pragma unroll
        for (int rr = 0; rr < 4; ++rr) {
            const float val = acc[f][rr] * rstd_r[rr] - mur_r[rr] * swc + cbc;
            outb[(size_t)(orow0 + rr) * MID_ + col] = (__bf16)val;
            colsum += val;
        }
        if (half == 0) {
            colsum += __shfl_xor(colsum, 16, 64);
            colsum += __shfl_xor(colsum, 32, 64);
            if (l4 == 0) atomicAdd(&part[batch * MID_ + col], colsum);
        }
    }
}

// ---------------------------------------------------------------------------
// K_mlp: gvec mean from part, MLP (96->24 relu ->4), softmax -> wts [8,4]
// ---------------------------------------------------------------------------
__global__ __launch_bounds__(128) void k_mlp(const float* __restrict__ part,
        const float* __restrict__ m1w, const float* __restrict__ m1b,
        const float* __restrict__ m2w, const float* __restrict__ m2b,
        float* __restrict__ wts) {
    const int b = blockIdx.x, t = threadIdx.x;
    __shared__ float gv[96];
    __shared__ float hid[24];
    __shared__ float lg[4];
    if (t < 96) gv[t] = part[b * MID_ + t] * (1.f / 4096.f);
    __syncthreads();
    if (t < 24) {
        float s = m1b[t];
        for (int c = 0; c < 96; ++c) s += gv[c] * m1w[t * 96 + c];
        hid[t] = fmaxf(s, 0.f);
    }
    __syncthreads();
    if (t < 4) {
        float s = m2b[t];
        for (int j = 0; j < 24; ++j) s += hid[j] * m2w[t * 24 + j];
        lg[t] = s;
    }
    __syncthreads();
    if (t < 4) {
        const float m = fmaxf(fmaxf(lg[0], lg[1]), fmaxf(lg[2], lg[3]));
        const float e = __expf(lg[t] - m);
        const float sum = __expf(lg[0] - m) + __expf(lg[1] - m) +
                          __expf(lg[2] - m) + __expf(lg[3] - m);
        wts[b * 4 + t] = e / sum;
    }
}

// ---------------------------------------------------------------------------
// K_dyn: precompute dyn kernels once per batch: dyng[b][pq][c].
// ---------------------------------------------------------------------------
__global__ __launch_bounds__(256) void k_dyn(const float* __restrict__ wts,
        const float* __restrict__ basis, float* __restrict__ dyng) {
    const int idx = blockIdx.x * 256 + threadIdx.x;
    if (idx >= 8 * 4704) return;
    const int b = idx / 4704;
    const int rem = idx - b * 4704;     // pq*96 + c
    const int pq = rem / 96;
    const int c = rem - pq * 96;
    const size_t off = (size_t)c * 49 + pq;
    dyng[idx] = wts[b * 4 + 0] * basis[off] +
                wts[b * 4 + 1] * basis[off + 4704] +
                wts[b * 4 + 2] * basis[off + 9408] +
                wts[b * 4 + 3] * basis[off + 14112];
}

// ---------------------------------------------------------------------------
// K_dwconv: depthwise 3x3 conv (zero pad) + SiLU. temb bf16 -> y bf16.
// ---------------------------------------------------------------------------
__global__ __launch_bounds__(256) void k_dwconv(const __bf16* __restrict__ temb,
        const float* __restrict__ dww, const float* __restrict__ dwb,
        __bf16* __restrict__ y) {
    __shared__ float wls[96 * 9];
    __shared__ float bls[96];
    const int t = threadIdx.x;
    for (int i = t; i < 96 * 9; i += 256) wls[i] = dww[i];
    if (t < 96) bls[t] = dwb[t];
    __syncthreads();
    const int b = blockIdx.x >> 6, h = blockIdx.x & 63;
    const __bf16* base = temb + (size_t)b * 4096 * MID_;
    for (int o = t; o < 64 * 96; o += 256) {
        const int w = o / 96;
        const int c = o - w * 96;
        float acc = bls[c];
#pragma unroll
        for (int dh = 0; dh < 3; ++dh) {
            const int hh = h + dh - 1;
            if (hh < 0 || hh > 63) continue;
#pragma unroll
            for (int dw = 0; dw < 3; ++dw) {
                const int ww = w + dw - 1;
                if (ww < 0 || ww > 63) continue;
                acc += (float)base[((size_t)hh * 64 + ww) * MID_ + c] *
                       wls[c * 9 + dh * 3 + dw];
            }
        }
        y[((size_t)(b * 64 + h) * 64 + w) * MID_ + c] =
            (__bf16)(acc / (1.f + __expf(-acc)));
    }
}

// ---------------------------------------------------------------------------
// K_style: style GEMM (y @ pw_w^T + pw_b) fused with modulation:
// common = x_emb * (1 + gamma) + beta -> bf16. K=96 fully staged, 1 barrier.
// ---------------------------------------------------------------------------
__global__ __launch_bounds__(256) void k_style(const __bf16* __restrict__ y,
        const __bf16* __restrict__ wpw, const float* __restrict__ pwb,
        const __bf16* __restrict__ xemb, __bf16* __restrict__ common) {
    __shared__ bf16x8 As[64][13];
    __shared__ bf16x8 Bs[192][13];
    const int t = threadIdx.x;
    const int row0 = blockIdx.x * 64;
    for (int idx = t; idx < 768; idx += 256) {
        const int rr = idx / 12, q = idx - rr * 12;
        As[rr][q] = *reinterpret_cast<const bf16x8*>(
            y + (size_t)(row0 + rr) * MID_ + q * 8);
    }
    for (int idx = t; idx < 2304; idx += 256) {
        const int rr = idx / 12, q = idx - rr * 12;
        Bs[rr][q] = *reinterpret_cast<const bf16x8*>(
            wpw + (size_t)rr * MID_ + q * 8);
    }
    __syncthreads();
    const int lane = t & 63, wave = t >> 6;
    const int l15 = lane & 15, l4 = lane >> 4;
    f32x4 acc[12] = {};
    const int ar = wave * 16 + l15;
#pragma unroll
    for (int kt = 0; kt < 3; ++kt) {
        bf16x8 a = As[ar][kt * 4 + l4];
#pragma unroll
        for (int f = 0; f < 12; ++f) {
            bf16x8 b = Bs[f * 16 + l15][kt * 4 + l4];
            acc[f] = __builtin_amdgcn_mfma_f32_16x16x32_bf16(a, b, acc[f], 0, 0, 0);
        }
    }
    const int orow = row0 + wave * 16 + l4 * 4;
#pragma unroll
    for (int f = 0; f < 6; ++f) {
        const int col = f * 16 + l15;
        const float pbg = pwb[col];
        const float pbb = pwb[col + 96];
#pragma unroll
        for (int rr = 0; rr < 4; ++rr) {
            const float g = acc[f][rr] + pbg;
            const float bt = acc[f + 6][rr] + pbb;
            const float xe = (float)xemb[(size_t)(orow + rr) * MID_ + col];
            common[(size_t)(orow + rr) * MID_ + col] = (__bf16)(xe * (1.f + g) + bt);
        }
    }
}

// ---------------------------------------------------------------------------
// K_circ v2: circular 7x7 conv. dyn from dyng; guard-free sliding window.
// ---------------------------------------------------------------------------
__global__ __launch_bounds__(192) void k_circ(const __bf16* __restrict__ common,
        const float* __restrict__ dyng, __bf16* __restrict__ outc) {
    __shared__ float dyn[49 * 96];
    const int t = threadIdx.x;
    const int b = blockIdx.x >> 7;
    const int h = (blockIdx.x >> 1) & 63;
    const int wslice = blockIdx.x & 1;
    const float* dsrc = dyng + (size_t)b * 4704;
    for (int idx = t; idx < 4704; idx += 192) dyn[idx] = dsrc[idx];
    __syncthreads();
    const int c = t % 96;
    const int wg = t / 96;
    const int wbase = wslice * 32 + wg * 16;
    const __bf16* cb = common + (size_t)b * 4096 * MID_ + c;
    float acc[16] = {};
#pragma unroll 1
    for (int p = 0; p < 7; ++p) {
        const int hh = (h + 3 - p) & 63;
        const __bf16* rp = cb + (size_t)hh * 64 * MID_;
        float dynr[7];
#pragma unroll
        for (int q = 0; q < 7; ++q) dynr[q] = dyn[(p * 7 + q) * 96 + c];
        float win[22];
#pragma unroll
        for (int i = 0; i < 22; ++i)
            win[i] = (float)rp[(size_t)((wbase - 3 + i) & 63) * MID_];
#pragma unroll
        for (int li = 0; li < 16; ++li) {
            float a = acc[li];
#pragma unroll
            for (int q = 0; q < 7; ++q) a += dynr[q] * win[li + 6 - q];
            acc[li] = a;
        }
    }
    const size_t obase = ((size_t)(b * 64 + h) * 64 + wbase) * MID_ + c;
#pragma unroll
    for (int li = 0; li < 16; ++li)
        outc[obase + (size_t)li * MID_] = (__bf16)acc[li];
}

// ---------------------------------------------------------------------------
// K_up: out = a_in[32768,96] @ up_w_bf16[768,96]^T + up_b + x  (fp32 out)
// ---------------------------------------------------------------------------
__global__ __launch_bounds__(256) void k_up(const __bf16* __restrict__ a_in,
        const __bf16* __restrict__ wbf, const float* __restrict__ upb,
        const float* __restrict__ x, float* __restrict__ out) {
    __shared__ bf16x8 As[128][13];
    __shared__ bf16x8 Ws[96][13];
    const int t = threadIdx.x;
    const int mt = blockIdx.x >> 3, nt = blockIdx.x & 7;
    const int row0 = mt * 128, col0 = nt * 96;
    for (int idx = t; idx < 1536; idx += 256) {
        const int rr = idx / 12, q = idx - rr * 12;
        As[rr][q] = *reinterpret_cast<const bf16x8*>(
            a_in + (size_t)(row0 + rr) * MID_ + q * 8);
    }
    for (int idx = t; idx < 1152; idx += 256) {
        const int rr = idx / 12, q = idx - rr * 12;
        Ws[rr][q] = *reinterpret_cast<const bf16x8*>(
            wbf + (size_t)(col0 + rr) * MID_ + q * 8);
    }
    __syncthreads();
    const int lane = t & 63, wave = t >> 6;
    const int l15 = lane & 15, l4 = lane >> 4;
    f32x4 acc[2][6] = {};
#pragma unroll
    for (int kt = 0; kt < 3; ++kt) {
        bf16x8 a0 = As[wave * 32 + l15][kt * 4 + l4];
        bf16x8 a1 = As[wave * 32 + 16 + l15][kt * 4 + l4];
#pragma unroll
        for (int f = 0; f < 6; ++f) {
            bf16x8 b = Ws[f * 16 + l15][kt * 4 + l4];
            acc[0][f] = __builtin_amdgcn_mfma_f32_16x16x32_bf16(a0, b, acc[0][f], 0, 0, 0);
            acc[1][f] = __builtin_amdgcn_mfma_f32_16x16x32_bf16(a1, b, acc[1][f], 0, 0, 0);
        }
    }
#pragma unroll
    for (int mr = 0; mr < 2; ++mr) {
        const int orow = row0 + wave * 32 + mr * 16 + l4 * 4;
#pragma unroll
        for (int f = 0; f < 6; ++f) {
            const int col = col0 + f * 16 + l15;
            const float ub = upb[col];
#pragma unroll
            for (int rr = 0; rr < 4; ++rr) {
                const size_t idx = (size_t)(orow + rr) * DIM_ + col;
                out[idx] = acc[mr][f][rr] + ub + x[idx];
            }
        }
    }
}

// ---------------------------------------------------------------------------
extern "C" void kernel_launch(void* const* d_in, const int* in_sizes, int n_in,
                              void* d_out, int out_size, void* d_ws, size_t ws_size,
                              hipStream_t stream) {
    (void)in_sizes; (void)n_in; (void)out_size; (void)ws_size;
    const float* x      = (const float*)d_in[0];
    const float* tt     = (const float*)d_in[1];
    const float* ln_w   = (const float*)d_in[2];
    const float* ln_b   = (const float*)d_in[3];
    const float* down_w = (const float*)d_in[4];
    const float* down_b = (const float*)d_in[5];
    const float* ln1_w  = (const float*)d_in[6];
    const float* ln1_b  = (const float*)d_in[7];
    const float* down1_w= (const float*)d_in[8];
    const float* down1_b= (const float*)d_in[9];
    const float* dw_w   = (const float*)d_in[10];
    const float* dw_b   = (const float*)d_in[11];
    const float* pw_w   = (const float*)d_in[12];
    const float* pw_b   = (const float*)d_in[13];
    const float* m1w    = (const float*)d_in[14];
    const float* m1b    = (const float*)d_in[15];
    const float* m2w    = (const float*)d_in[16];
    const float* m2b    = (const float*)d_in[17];
    const float* basis  = (const float*)d_in[18];
    const float* up_w   = (const float*)d_in[19];
    const float* up_b   = (const float*)d_in[20];
    float* out = (float*)d_out;
    char* ws = (char*)d_ws;

    // workspace layout (bytes)
    __bf16* wln_down  = (__bf16*)(ws + 0);          // 96*768*2  = 147456
    __bf16* wln_down1 = (__bf16*)(ws + 147456);
    __bf16* wbf_up    = (__bf16*)(ws + 294912);     // 768*96*2
    __bf16* wbf_pw    = (__bf16*)(ws + 442368);     // 192*96*2 = 36864
    float*  part      = (float*)(ws + 479232);      // 8*96*4 = 3072
    float*  wts       = (float*)(ws + 482304);      // 32*4
    float*  swcb      = (float*)(ws + 482560);      // 2*192*4 = 1536
    __bf16* x_emb     = (__bf16*)(ws + 524288);     // 32768*96*2 = 6291456
    __bf16* t_emb     = (__bf16*)(ws + 6815744);
    __bf16* ybuf      = (__bf16*)(ws + 13107200);
    __bf16* common    = (__bf16*)(ws + 19398656);
    __bf16* convout   = (__bf16*)(ws + 25690112);
    float*  dyng      = (float*)(ws + 31981568);    // 8*49*96*4 = 150528

    // opt-in to >64KB dynamic LDS for k_downf (not a stream op; capture-safe)
    (void)hipFuncSetAttribute((const void*)k_downf,
                              hipFuncAttributeMaxDynamicSharedMemorySize, 73728);

    k_prep<<<141, 256, 0, stream>>>(down_w, down_b, ln_w, ln_b,
                                    down1_w, down1_b, ln1_w, ln1_b,
                                    wln_down, wln_down1, swcb,
                                    up_w, pw_w, wbf_up, wbf_pw, part);
    k_downf<<<512, 1024, 73728, stream>>>(x, tt, wln_down, wln_down1, swcb,
                                          x_emb, t_emb, part);
    k_mlp<<<8, 128, 0, stream>>>(part, m1w, m1b, m2w, m2b, wts);
    k_dyn<<<147, 256, 0, stream>>>(wts, basis, dyng);
    k_dwconv<<<512, 256, 0, stream>>>(t_emb, dw_w, dw_b, ybuf);
    k_style<<<512, 256, 0, stream>>>(ybuf, wbf_pw, pw_b, x_emb, common);
    k_circ<<<1024, 192, 0, stream>>>(common, dyng, convout);
    k_up<<<2048, 256, 0, stream>>>(convout, wbf_up, up_b, x, out);
}

// Round 17
// 173.404 us; speedup vs baseline: 1.3688x; 1.1717x over previous
//
#include <hip/hip_runtime.h>

#define DIM_ 768
#define MID_ 96

typedef float f32x4 __attribute__((ext_vector_type(4)));
typedef __bf16 bf16x8 __attribute__((ext_vector_type(8)));
typedef __bf16 bf16x4 __attribute__((ext_vector_type(4)));

// ---------------------------------------------------------------------------
// K_prep: fused weight prep.
// Blocks [0,48): fold LN scale into down/down1 weights; sw/cb constants.
// Blocks [48,141): bf16-cast up_w, pw_w; zero gvec partials.
// ---------------------------------------------------------------------------
__global__ __launch_bounds__(256) void k_prep(
        const float* __restrict__ dw, const float* __restrict__ db,
        const float* __restrict__ lnw0, const float* __restrict__ lnb0,
        const float* __restrict__ d1w, const float* __restrict__ d1b,
        const float* __restrict__ lnw1, const float* __restrict__ lnb1,
        __bf16* __restrict__ wln0, __bf16* __restrict__ wln1,
        float* __restrict__ swcb,
        const float* __restrict__ uw, const float* __restrict__ pw,
        __bf16* __restrict__ bup, __bf16* __restrict__ bpw,
        float* __restrict__ part) {
    if (blockIdx.x >= 48) {
        const int t = (blockIdx.x - 48) * 256 + threadIdx.x;
        const float* src;
        __bf16* dst;
        int i;
        if (t < 18432)      { src = uw; dst = bup; i = t; }
        else if (t < 23040) { src = pw; dst = bpw; i = t - 18432; }
        else if (t < 23808) { part[t - 23040] = 0.f; return; }
        else return;
        float4 v = reinterpret_cast<const float4*>(src)[i];
        bf16x4 o;
        o[0] = (__bf16)v.x; o[1] = (__bf16)v.y;
        o[2] = (__bf16)v.z; o[3] = (__bf16)v.w;
        *reinterpret_cast<bf16x4*>(dst + (size_t)i * 4) = o;
        return;
    }
    const int wid = blockIdx.x * 4 + (threadIdx.x >> 6);
    const int lane = threadIdx.x & 63;
    const int mat = wid >= 96;
    const int n = mat ? wid - 96 : wid;
    const float* W   = mat ? d1w : dw;
    const float* bia = mat ? d1b : db;
    const float* lw  = mat ? lnw1 : lnw0;
    const float* lb  = mat ? lnb1 : lnb0;
    __bf16* dst = mat ? wln1 : wln0;
    float sacc = 0.f, cacc = 0.f;
#pragma unroll
    for (int j = 0; j < 12; ++j) {
        const int k = j * 64 + lane;
        const float w = W[(size_t)n * DIM_ + k];
        const float val = w * lw[k];
        const __bf16 bv = (__bf16)val;
        dst[(size_t)n * DIM_ + k] = bv;
        sacc += (float)bv;
        cacc += lb[k] * w;
    }
#pragma unroll
    for (int m = 1; m < 64; m <<= 1) {
        sacc += __shfl_xor(sacc, m, 64);
        cacc += __shfl_xor(cacc, m, 64);
    }
    if (lane == 0) {
        swcb[mat * 192 + n] = sacc;               // sw
        swcb[mat * 192 + 96 + n] = cacc + bia[n]; // cb
    }
}

// ---------------------------------------------------------------------------
// K_downf: r8/r14 version — best of 12 down-path variants (91 us; also the
// best-total configuration). Fused LN+GEMM for BOTH x and t, W (147 KB)
// LDS-resident in fragment order, bf16 depth-2 pipeline fitting 64 VGPR.
// LN algebraic: out = acc*rstd - mu*rstd*sw + cb.
// ---------------------------------------------------------------------------
__global__ __launch_bounds__(1024)
__attribute__((amdgpu_waves_per_eu(4, 4)))
void k_downf(
        const float* __restrict__ xsrc, const float* __restrict__ tsrc,
        const __bf16* __restrict__ wln0, const __bf16* __restrict__ wln1,
        const float* __restrict__ swcb, __bf16* __restrict__ xemb,
        __bf16* __restrict__ temb, float* __restrict__ part) {
    extern __shared__ __bf16 Wp[];   // 96*768 = 73728 elems = 147456 B
    const int t = threadIdx.x;
    const int half = blockIdx.x >> 7;      // 0: x, 1: t
    const int mb = blockIdx.x & 127;
    const float* src = half ? tsrc : xsrc;
    const __bf16* wln = half ? wln1 : wln0;
    const float* sc = swcb + half * 192;
    __bf16* outb = half ? temb : xemb;

#pragma unroll
    for (int i = 0; i < 9; ++i) {
        const int idx = t + i * 1024;          // 0..9215
        const int ls = idx & 63;
        const int rem = idx >> 6;              // kt*6 + f
        const int kt = rem / 6;
        const int f = rem - kt * 6;
        const int row = f * 16 + (ls & 15);
        const int col = kt * 32 + (ls >> 4) * 8;
        *reinterpret_cast<bf16x8*>(Wp + (size_t)idx * 8) =
            *reinterpret_cast<const bf16x8*>(wln + (size_t)row * DIM_ + col);
    }
    __syncthreads();

    const int lane = t & 63, wave = t >> 6;   // 16 waves
    const int l15 = lane & 15, l4 = lane >> 4;
    const int row = mb * 256 + wave * 16 + l15;
    const float* rp = src + (size_t)row * DIM_ + l4 * 8;

    float s = 0.f, sq = 0.f;
    f32x4 acc[6] = {};

    auto cvt = [&](const float4& v0, const float4& v1) -> bf16x8 {
        s += v0.x + v0.y + v0.z + v0.w + v1.x + v1.y + v1.z + v1.w;
        sq += v0.x * v0.x + v0.y * v0.y + v0.z * v0.z + v0.w * v0.w +
              v1.x * v1.x + v1.y * v1.y + v1.z * v1.z + v1.w * v1.w;
        bf16x8 a;
        a[0] = (__bf16)v0.x; a[1] = (__bf16)v0.y;
        a[2] = (__bf16)v0.z; a[3] = (__bf16)v0.w;
        a[4] = (__bf16)v1.x; a[5] = (__bf16)v1.y;
        a[6] = (__bf16)v1.z; a[7] = (__bf16)v1.w;
        return a;
    };
    auto consume = [&](const bf16x8& a, int kt) {
        const __bf16* bp = Wp + ((size_t)(kt * 6) * 64 + lane) * 8;
#pragma unroll
        for (int f = 0; f < 6; ++f) {
            bf16x8 b = *reinterpret_cast<const bf16x8*>(bp + (size_t)f * 64 * 8);
            acc[f] = __builtin_amdgcn_mfma_f32_16x16x32_bf16(a, b, acc[f], 0, 0, 0);
        }
    };

    float4 w0a = *reinterpret_cast<const float4*>(rp + 0);
    float4 w0b = *reinterpret_cast<const float4*>(rp + 4);
    float4 w1a = *reinterpret_cast<const float4*>(rp + 32);
    float4 w1b = *reinterpret_cast<const float4*>(rp + 36);
    bf16x8 a0 = cvt(w0a, w0b);
    bf16x8 a1 = cvt(w1a, w1b);
    w0a = *reinterpret_cast<const float4*>(rp + 64);
    w0b = *reinterpret_cast<const float4*>(rp + 68);
    w1a = *reinterpret_cast<const float4*>(rp + 96);
    w1b = *reinterpret_cast<const float4*>(rp + 100);
#pragma unroll
    for (int kt = 0; kt < 24; kt += 2) {
        consume(a0, kt);
        if (kt + 2 < 24) {
            a0 = cvt(w0a, w0b);
            if (kt + 4 < 24) {
                w0a = *reinterpret_cast<const float4*>(rp + (kt + 4) * 32);
                w0b = *reinterpret_cast<const float4*>(rp + (kt + 4) * 32 + 4);
            }
        }
        consume(a1, kt + 1);
        if (kt + 3 < 24) {
            a1 = cvt(w1a, w1b);
            if (kt + 5 < 24) {
                w1a = *reinterpret_cast<const float4*>(rp + (kt + 5) * 32);
                w1b = *reinterpret_cast<const float4*>(rp + (kt + 5) * 32 + 4);
            }
        }
    }

    s += __shfl_xor(s, 16, 64); sq += __shfl_xor(sq, 16, 64);
    s += __shfl_xor(s, 32, 64); sq += __shfl_xor(sq, 32, 64);
    const float mean = s * (1.f / 768.f);
    const float rstd = rsqrtf(sq * (1.f / 768.f) - mean * mean + 1e-6f);
    const float mur = mean * rstd;
    float rstd_r[4], mur_r[4];
#pragma unroll
    for (int rr = 0; rr < 4; ++rr) {
        rstd_r[rr] = __shfl(rstd, l4 * 4 + rr, 64);
        mur_r[rr]  = __shfl(mur,  l4 * 4 + rr, 64);
    }

    const int orow0 = mb * 256 + wave * 16 + l4 * 4;
    const int batch = mb >> 4;     // 16 blocks per image
#pragma unroll
    for (int f = 0; f < 6; ++f) {
        const int col = f * 16 + l15;
        const float swc = sc[col];
        const float cbc = sc[96 + col];
        float colsum = 0.f;
#pragma unroll
        for (int rr = 0; rr < 4; ++rr) {
            const float val = acc[f][rr] * rstd_r[rr] - mur_r[rr] * swc + cbc;
            outb[(size_t)(orow0 + rr) * MID_ + col] = (__bf16)val;
            colsum += val;
        }
        if (half == 0) {
            colsum += __shfl_xor(colsum, 16, 64);
            colsum += __shfl_xor(colsum, 32, 64);
            if (l4 == 0) atomicAdd(&part[batch * MID_ + col], colsum);
        }
    }
}

// ---------------------------------------------------------------------------
// K_mlpdyn: fused MLP+softmax (per-block recompute, cheap: 96*24+24*4 fma)
// and dyn-kernel build: dyng[b][pq][c] = sum_k wts[b][k]*basis[k][c][pq].
// Grid 148 x 256; block covers 256 dyng elems; wts recomputed per block
// (no cross-block dependency, one launch saved vs k_mlp + k_dyn).
// ---------------------------------------------------------------------------
__global__ __launch_bounds__(256) void k_mlpdyn(const float* __restrict__ part,
        const float* __restrict__ m1w, const float* __restrict__ m1b,
        const float* __restrict__ m2w, const float* __restrict__ m2b,
        const float* __restrict__ basis, float* __restrict__ dyng) {
    const int gidx = blockIdx.x * 256 + threadIdx.x;
    const int b = gidx / 4704;
    if (b >= 8) return;
    __shared__ float gv[96];
    __shared__ float hid[24];
    __shared__ float wls[4];
    const int t = threadIdx.x;
    // all threads of a block share one b only if the block doesn't straddle
    // a batch boundary; recompute per-thread-batch via block-uniform path:
    // blocks are 256 elems; 4704 % 256 != 0, so a block can straddle two b.
    // Handle by computing wts for BOTH candidate batches in LDS.
    const int b0 = (blockIdx.x * 256) / 4704;
    const int b1 = (blockIdx.x * 256 + 255) / 4704;
    __shared__ float wts2[2][4];
    for (int bi = 0; bi <= (b1 > b0 && b1 < 8 ? 1 : 0); ++bi) {
        const int bb = bi ? b1 : b0;
        if (t < 96) gv[t] = part[bb * MID_ + t] * (1.f / 4096.f);
        __syncthreads();
        if (t < 24) {
            float s = m1b[t];
            for (int c = 0; c < 96; ++c) s += gv[c] * m1w[t * 96 + c];
            hid[t] = fmaxf(s, 0.f);
        }
        __syncthreads();
        if (t < 4) {
            float s = m2b[t];
            for (int j = 0; j < 24; ++j) s += hid[j] * m2w[t * 24 + j];
            wls[t] = s;
        }
        __syncthreads();
        if (t < 4) {
            const float m = fmaxf(fmaxf(wls[0], wls[1]), fmaxf(wls[2], wls[3]));
            const float e = __expf(wls[t] - m);
            const float sum = __expf(wls[0] - m) + __expf(wls[1] - m) +
                              __expf(wls[2] - m) + __expf(wls[3] - m);
            wts2[bi][t] = e / sum;
        }
        __syncthreads();
    }
    const int rem = gidx - b * 4704;     // pq*96 + c
    const int pq = rem / 96;
    const int c = rem - pq * 96;
    const size_t off = (size_t)c * 49 + pq;
    const float* w = wts2[(b == b0) ? 0 : 1];
    dyng[gidx] = w[0] * basis[off] + w[1] * basis[off + 4704] +
                 w[2] * basis[off + 9408] + w[3] * basis[off + 14112];
}

// ---------------------------------------------------------------------------
// K_dwconv: depthwise 3x3 conv (zero pad) + SiLU. temb bf16 -> y bf16.
// ---------------------------------------------------------------------------
__global__ __launch_bounds__(256) void k_dwconv(const __bf16* __restrict__ temb,
        const float* __restrict__ dww, const float* __restrict__ dwb,
        __bf16* __restrict__ y) {
    __shared__ float wls[96 * 9];
    __shared__ float bls[96];
    const int t = threadIdx.x;
    for (int i = t; i < 96 * 9; i += 256) wls[i] = dww[i];
    if (t < 96) bls[t] = dwb[t];
    __syncthreads();
    const int b = blockIdx.x >> 6, h = blockIdx.x & 63;
    const __bf16* base = temb + (size_t)b * 4096 * MID_;
    for (int o = t; o < 64 * 96; o += 256) {
        const int w = o / 96;
        const int c = o - w * 96;
        float acc = bls[c];
#pragma unroll
        for (int dh = 0; dh < 3; ++dh) {
            const int hh = h + dh - 1;
            if (hh < 0 || hh > 63) continue;
#pragma unroll
            for (int dw = 0; dw < 3; ++dw) {
                const int ww = w + dw - 1;
                if (ww < 0 || ww > 63) continue;
                acc += (float)base[((size_t)hh * 64 + ww) * MID_ + c] *
                       wls[c * 9 + dh * 3 + dw];
            }
        }
        y[((size_t)(b * 64 + h) * 64 + w) * MID_ + c] =
            (__bf16)(acc / (1.f + __expf(-acc)));
    }
}

// ---------------------------------------------------------------------------
// K_style: style GEMM (y @ pw_w^T + pw_b) fused with modulation:
// common = x_emb * (1 + gamma) + beta -> bf16. K=96 fully staged, 1 barrier.
// ---------------------------------------------------------------------------
__global__ __launch_bounds__(256) void k_style(const __bf16* __restrict__ y,
        const __bf16* __restrict__ wpw, const float* __restrict__ pwb,
        const __bf16* __restrict__ xemb, __bf16* __restrict__ common) {
    __shared__ bf16x8 As[64][13];
    __shared__ bf16x8 Bs[192][13];
    const int t = threadIdx.x;
    const int row0 = blockIdx.x * 64;
    for (int idx = t; idx < 768; idx += 256) {
        const int rr = idx / 12, q = idx - rr * 12;
        As[rr][q] = *reinterpret_cast<const bf16x8*>(
            y + (size_t)(row0 + rr) * MID_ + q * 8);
    }
    for (int idx = t; idx < 2304; idx += 256) {
        const int rr = idx / 12, q = idx - rr * 12;
        Bs[rr][q] = *reinterpret_cast<const bf16x8*>(
            wpw + (size_t)rr * MID_ + q * 8);
    }
    __syncthreads();
    const int lane = t & 63, wave = t >> 6;
    const int l15 = lane & 15, l4 = lane >> 4;
    f32x4 acc[12] = {};
    const int ar = wave * 16 + l15;
#pragma unroll
    for (int kt = 0; kt < 3; ++kt) {
        bf16x8 a = As[ar][kt * 4 + l4];
#pragma unroll
        for (int f = 0; f < 12; ++f) {
            bf16x8 b = Bs[f * 16 + l15][kt * 4 + l4];
            acc[f] = __builtin_amdgcn_mfma_f32_16x16x32_bf16(a, b, acc[f], 0, 0, 0);
        }
    }
    const int orow = row0 + wave * 16 + l4 * 4;
#pragma unroll
    for (int f = 0; f < 6; ++f) {
        const int col = f * 16 + l15;
        const float pbg = pwb[col];
        const float pbb = pwb[col + 96];
#pragma unroll
        for (int rr = 0; rr < 4; ++rr) {
            const float g = acc[f][rr] + pbg;
            const float bt = acc[f + 6][rr] + pbb;
            const float xe = (float)xemb[(size_t)(orow + rr) * MID_ + col];
            common[(size_t)(orow + rr) * MID_ + col] = (__bf16)(xe * (1.f + g) + bt);
        }
    }
}

// ---------------------------------------------------------------------------
// K_circ: circular 7x7 conv. dyn from dyng; guard-free sliding window.
// ---------------------------------------------------------------------------
__global__ __launch_bounds__(192) void k_circ(const __bf16* __restrict__ common,
        const float* __restrict__ dyng, __bf16* __restrict__ outc) {
    __shared__ float dyn[49 * 96];
    const int t = threadIdx.x;
    const int b = blockIdx.x >> 7;
    const int h = (blockIdx.x >> 1) & 63;
    const int wslice = blockIdx.x & 1;
    const float* dsrc = dyng + (size_t)b * 4704;
    for (int idx = t; idx < 4704; idx += 192) dyn[idx] = dsrc[idx];
    __syncthreads();
    const int c = t % 96;
    const int wg = t / 96;
    const int wbase = wslice * 32 + wg * 16;
    const __bf16* cb = common + (size_t)b * 4096 * MID_ + c;
    float acc[16] = {};
#pragma unroll 1
    for (int p = 0; p < 7; ++p) {
        const int hh = (h + 3 - p) & 63;
        const __bf16* rp = cb + (size_t)hh * 64 * MID_;
        float dynr[7];
#pragma unroll
        for (int q = 0; q < 7; ++q) dynr[q] = dyn[(p * 7 + q) * 96 + c];
        float win[22];
#pragma unroll
        for (int i = 0; i < 22; ++i)
            win[i] = (float)rp[(size_t)((wbase - 3 + i) & 63) * MID_];
#pragma unroll
        for (int li = 0; li < 16; ++li) {
            float a = acc[li];
#pragma unroll
            for (int q = 0; q < 7; ++q) a += dynr[q] * win[li + 6 - q];
            acc[li] = a;
        }
    }
    const size_t obase = ((size_t)(b * 64 + h) * 64 + wbase) * MID_ + c;
#pragma unroll
    for (int li = 0; li < 16; ++li)
        outc[obase + (size_t)li * MID_] = (__bf16)acc[li];
}

// ---------------------------------------------------------------------------
// K_up: out = a_in[32768,96] @ up_w_bf16[768,96]^T + up_b + x  (fp32 out)
// ---------------------------------------------------------------------------
__global__ __launch_bounds__(256) void k_up(const __bf16* __restrict__ a_in,
        const __bf16* __restrict__ wbf, const float* __restrict__ upb,
        const float* __restrict__ x, float* __restrict__ out) {
    __shared__ bf16x8 As[128][13];
    __shared__ bf16x8 Ws[96][13];
    const int t = threadIdx.x;
    const int mt = blockIdx.x >> 3, nt = blockIdx.x & 7;
    const int row0 = mt * 128, col0 = nt * 96;
    for (int idx = t; idx < 1536; idx += 256) {
        const int rr = idx / 12, q = idx - rr * 12;
        As[rr][q] = *reinterpret_cast<const bf16x8*>(
            a_in + (size_t)(row0 + rr) * MID_ + q * 8);
    }
    for (int idx = t; idx < 1152; idx += 256) {
        const int rr = idx / 12, q = idx - rr * 12;
        Ws[rr][q] = *reinterpret_cast<const bf16x8*>(
            wbf + (size_t)(col0 + rr) * MID_ + q * 8);
    }
    __syncthreads();
    const int lane = t & 63, wave = t >> 6;
    const int l15 = lane & 15, l4 = lane >> 4;
    f32x4 acc[2][6] = {};
#pragma unroll
    for (int kt = 0; kt < 3; ++kt) {
        bf16x8 a0 = As[wave * 32 + l15][kt * 4 + l4];
        bf16x8 a1 = As[wave * 32 + 16 + l15][kt * 4 + l4];
#pragma unroll
        for (int f = 0; f < 6; ++f) {
            bf16x8 b = Ws[f * 16 + l15][kt * 4 + l4];
            acc[0][f] = __builtin_amdgcn_mfma_f32_16x16x32_bf16(a0, b, acc[0][f], 0, 0, 0);
            acc[1][f] = __builtin_amdgcn_mfma_f32_16x16x32_bf16(a1, b, acc[1][f], 0, 0, 0);
        }
    }
#pragma unroll
    for (int mr = 0; mr < 2; ++mr) {
        const int orow = row0 + wave * 32 + mr * 16 + l4 * 4;
#pragma unroll
        for (int f = 0; f < 6; ++f) {
            const int col = col0 + f * 16 + l15;
            const float ub = upb[col];
#pragma unroll
            for (int rr = 0; rr < 4; ++rr) {
                const size_t idx = (size_t)(orow + rr) * DIM_ + col;
                out[idx] = acc[mr][f][rr] + ub + x[idx];
            }
        }
    }
}

// ---------------------------------------------------------------------------
extern "C" void kernel_launch(void* const* d_in, const int* in_sizes, int n_in,
                              void* d_out, int out_size, void* d_ws, size_t ws_size,
                              hipStream_t stream) {
    (void)in_sizes; (void)n_in; (void)out_size; (void)ws_size;
    const float* x      = (const float*)d_in[0];
    const float* tt     = (const float*)d_in[1];
    const float* ln_w   = (const float*)d_in[2];
    const float* ln_b   = (const float*)d_in[3];
    const float* down_w = (const float*)d_in[4];
    const float* down_b = (const float*)d_in[5];
    const float* ln1_w  = (const float*)d_in[6];
    const float* ln1_b  = (const float*)d_in[7];
    const float* down1_w= (const float*)d_in[8];
    const float* down1_b= (const float*)d_in[9];
    const float* dw_w   = (const float*)d_in[10];
    const float* dw_b   = (const float*)d_in[11];
    const float* pw_w   = (const float*)d_in[12];
    const float* pw_b   = (const float*)d_in[13];
    const float* m1w    = (const float*)d_in[14];
    const float* m1b    = (const float*)d_in[15];
    const float* m2w    = (const float*)d_in[16];
    const float* m2b    = (const float*)d_in[17];
    const float* basis  = (const float*)d_in[18];
    const float* up_w   = (const float*)d_in[19];
    const float* up_b   = (const float*)d_in[20];
    float* out = (float*)d_out;
    char* ws = (char*)d_ws;

    // workspace layout (bytes)
    __bf16* wln_down  = (__bf16*)(ws + 0);          // 96*768*2  = 147456
    __bf16* wln_down1 = (__bf16*)(ws + 147456);
    __bf16* wbf_up    = (__bf16*)(ws + 294912);     // 768*96*2
    __bf16* wbf_pw    = (__bf16*)(ws + 442368);     // 192*96*2 = 36864
    float*  part      = (float*)(ws + 479232);      // 8*96*4 = 3072
    float*  swcb      = (float*)(ws + 482560);      // 2*192*4 = 1536
    __bf16* x_emb     = (__bf16*)(ws + 524288);     // 32768*96*2 = 6291456
    __bf16* t_emb     = (__bf16*)(ws + 6815744);
    __bf16* ybuf      = (__bf16*)(ws + 13107200);
    __bf16* common    = (__bf16*)(ws + 19398656);
    __bf16* convout   = (__bf16*)(ws + 25690112);
    float*  dyng      = (float*)(ws + 31981568);    // 8*49*96*4 = 150528

    // opt-in to >64KB dynamic LDS for k_downf (not a stream op; capture-safe)
    (void)hipFuncSetAttribute((const void*)k_downf,
                              hipFuncAttributeMaxDynamicSharedMemorySize, 147456);

    k_prep<<<141, 256, 0, stream>>>(down_w, down_b, ln_w, ln_b,
                                    down1_w, down1_b, ln1_w, ln1_b,
                                    wln_down, wln_down1, swcb,
                                    up_w, pw_w, wbf_up, wbf_pw, part);
    k_downf<<<256, 1024, 147456, stream>>>(x, tt, wln_down, wln_down1, swcb,
                                           x_emb, t_emb, part);
    k_mlpdyn<<<148, 256, 0, stream>>>(part, m1w, m1b, m2w, m2b, basis, dyng);
    k_dwconv<<<512, 256, 0, stream>>>(t_emb, dw_w, dw_b, ybuf);
    k_style<<<512, 256, 0, stream>>>(ybuf, wbf_pw, pw_b, x_emb, common);
    k_circ<<<1024, 192, 0, stream>>>(common, dyng, convout);
    k_up<<<2048, 256, 0, stream>>>(convout, wbf_up, up_b, x, out);
}

// Round 18
// 129.286 us; speedup vs baseline: 1.8360x; 1.3412x over previous
//
#include <hip/hip_runtime.h>

#define DIM_ 768
#define MID_ 96

typedef float f32x4 __attribute__((ext_vector_type(4)));
typedef __bf16 bf16x8 __attribute__((ext_vector_type(8)));
typedef __bf16 bf16x4 __attribute__((ext_vector_type(4)));

// ---------------------------------------------------------------------------
// K_prep: fused weight prep.
// Blocks [0,48): fold LN scale into down/down1 weights; sw/cb constants.
// Blocks [48,141): bf16-cast up_w, pw_w; zero gvec partials.
// ---------------------------------------------------------------------------
__global__ __launch_bounds__(256) void k_prep(
        const float* __restrict__ dw, const float* __restrict__ db,
        const float* __restrict__ lnw0, const float* __restrict__ lnb0,
        const float* __restrict__ d1w, const float* __restrict__ d1b,
        const float* __restrict__ lnw1, const float* __restrict__ lnb1,
        __bf16* __restrict__ wln0, __bf16* __restrict__ wln1,
        float* __restrict__ swcb,
        const float* __restrict__ uw, const float* __restrict__ pw,
        __bf16* __restrict__ bup, __bf16* __restrict__ bpw,
        float* __restrict__ part) {
    if (blockIdx.x >= 48) {
        const int t = (blockIdx.x - 48) * 256 + threadIdx.x;
        const float* src;
        __bf16* dst;
        int i;
        if (t < 18432)      { src = uw; dst = bup; i = t; }
        else if (t < 23040) { src = pw; dst = bpw; i = t - 18432; }
        else if (t < 23808) { part[t - 23040] = 0.f; return; }
        else return;
        float4 v = reinterpret_cast<const float4*>(src)[i];
        bf16x4 o;
        o[0] = (__bf16)v.x; o[1] = (__bf16)v.y;
        o[2] = (__bf16)v.z; o[3] = (__bf16)v.w;
        *reinterpret_cast<bf16x4*>(dst + (size_t)i * 4) = o;
        return;
    }
    const int wid = blockIdx.x * 4 + (threadIdx.x >> 6);
    const int lane = threadIdx.x & 63;
    const int mat = wid >= 96;
    const int n = mat ? wid - 96 : wid;
    const float* W   = mat ? d1w : dw;
    const float* bia = mat ? d1b : db;
    const float* lw  = mat ? lnw1 : lnw0;
    const float* lb  = mat ? lnb1 : lnb0;
    __bf16* dst = mat ? wln1 : wln0;
    float sacc = 0.f, cacc = 0.f;
#pragma unroll
    for (int j = 0; j < 12; ++j) {
        const int k = j * 64 + lane;
        const float w = W[(size_t)n * DIM_ + k];
        const float val = w * lw[k];
        const __bf16 bv = (__bf16)val;
        dst[(size_t)n * DIM_ + k] = bv;
        sacc += (float)bv;
        cacc += lb[k] * w;
    }
#pragma unroll
    for (int m = 1; m < 64; m <<= 1) {
        sacc += __shfl_xor(sacc, m, 64);
        cacc += __shfl_xor(cacc, m, 64);
    }
    if (lane == 0) {
        swcb[mat * 192 + n] = sacc;               // sw
        swcb[mat * 192 + 96 + n] = cacc + bia[n]; // cb
    }
}

// ---------------------------------------------------------------------------
// K_downf: r8/r14 version — best of 12 down-path variants (~91 us; the
// invariant wall is the 64B-granular A-fragment gather, ~2.2 TB/s).
// ---------------------------------------------------------------------------
__global__ __launch_bounds__(1024)
__attribute__((amdgpu_waves_per_eu(4, 4)))
void k_downf(
        const float* __restrict__ xsrc, const float* __restrict__ tsrc,
        const __bf16* __restrict__ wln0, const __bf16* __restrict__ wln1,
        const float* __restrict__ swcb, __bf16* __restrict__ xemb,
        __bf16* __restrict__ temb, float* __restrict__ part) {
    extern __shared__ __bf16 Wp[];   // 96*768 = 73728 elems = 147456 B
    const int t = threadIdx.x;
    const int half = blockIdx.x >> 7;      // 0: x, 1: t
    const int mb = blockIdx.x & 127;
    const float* src = half ? tsrc : xsrc;
    const __bf16* wln = half ? wln1 : wln0;
    const float* sc = swcb + half * 192;
    __bf16* outb = half ? temb : xemb;

#pragma unroll
    for (int i = 0; i < 9; ++i) {
        const int idx = t + i * 1024;          // 0..9215
        const int ls = idx & 63;
        const int rem = idx >> 6;              // kt*6 + f
        const int kt = rem / 6;
        const int f = rem - kt * 6;
        const int row = f * 16 + (ls & 15);
        const int col = kt * 32 + (ls >> 4) * 8;
        *reinterpret_cast<bf16x8*>(Wp + (size_t)idx * 8) =
            *reinterpret_cast<const bf16x8*>(wln + (size_t)row * DIM_ + col);
    }
    __syncthreads();

    const int lane = t & 63, wave = t >> 6;   // 16 waves
    const int l15 = lane & 15, l4 = lane >> 4;
    const int row = mb * 256 + wave * 16 + l15;
    const float* rp = src + (size_t)row * DIM_ + l4 * 8;

    float s = 0.f, sq = 0.f;
    f32x4 acc[6] = {};

    auto cvt = [&](const float4& v0, const float4& v1) -> bf16x8 {
        s += v0.x + v0.y + v0.z + v0.w + v1.x + v1.y + v1.z + v1.w;
        sq += v0.x * v0.x + v0.y * v0.y + v0.z * v0.z + v0.w * v0.w +
              v1.x * v1.x + v1.y * v1.y + v1.z * v1.z + v1.w * v1.w;
        bf16x8 a;
        a[0] = (__bf16)v0.x; a[1] = (__bf16)v0.y;
        a[2] = (__bf16)v0.z; a[3] = (__bf16)v0.w;
        a[4] = (__bf16)v1.x; a[5] = (__bf16)v1.y;
        a[6] = (__bf16)v1.z; a[7] = (__bf16)v1.w;
        return a;
    };
    auto consume = [&](const bf16x8& a, int kt) {
        const __bf16* bp = Wp + ((size_t)(kt * 6) * 64 + lane) * 8;
#pragma unroll
        for (int f = 0; f < 6; ++f) {
            bf16x8 b = *reinterpret_cast<const bf16x8*>(bp + (size_t)f * 64 * 8);
            acc[f] = __builtin_amdgcn_mfma_f32_16x16x32_bf16(a, b, acc[f], 0, 0, 0);
        }
    };

    float4 w0a = *reinterpret_cast<const float4*>(rp + 0);
    float4 w0b = *reinterpret_cast<const float4*>(rp + 4);
    float4 w1a = *reinterpret_cast<const float4*>(rp + 32);
    float4 w1b = *reinterpret_cast<const float4*>(rp + 36);
    bf16x8 a0 = cvt(w0a, w0b);
    bf16x8 a1 = cvt(w1a, w1b);
    w0a = *reinterpret_cast<const float4*>(rp + 64);
    w0b = *reinterpret_cast<const float4*>(rp + 68);
    w1a = *reinterpret_cast<const float4*>(rp + 96);
    w1b = *reinterpret_cast<const float4*>(rp + 100);
#pragma unroll
    for (int kt = 0; kt < 24; kt += 2) {
        consume(a0, kt);
        if (kt + 2 < 24) {
            a0 = cvt(w0a, w0b);
            if (kt + 4 < 24) {
                w0a = *reinterpret_cast<const float4*>(rp + (kt + 4) * 32);
                w0b = *reinterpret_cast<const float4*>(rp + (kt + 4) * 32 + 4);
            }
        }
        consume(a1, kt + 1);
        if (kt + 3 < 24) {
            a1 = cvt(w1a, w1b);
            if (kt + 5 < 24) {
                w1a = *reinterpret_cast<const float4*>(rp + (kt + 5) * 32);
                w1b = *reinterpret_cast<const float4*>(rp + (kt + 5) * 32 + 4);
            }
        }
    }

    s += __shfl_xor(s, 16, 64); sq += __shfl_xor(sq, 16, 64);
    s += __shfl_xor(s, 32, 64); sq += __shfl_xor(sq, 32, 64);
    const float mean = s * (1.f / 768.f);
    const float rstd = rsqrtf(sq * (1.f / 768.f) - mean * mean + 1e-6f);
    const float mur = mean * rstd;
    float rstd_r[4], mur_r[4];
#pragma unroll
    for (int rr = 0; rr < 4; ++rr) {
        rstd_r[rr] = __shfl(rstd, l4 * 4 + rr, 64);
        mur_r[rr]  = __shfl(mur,  l4 * 4 + rr, 64);
    }

    const int orow0 = mb * 256 + wave * 16 + l4 * 4;
    const int batch = mb >> 4;     // 16 blocks per image
#pragma unroll
    for (int f = 0; f < 6; ++f) {
        const int col = f * 16 + l15;
        const float swc = sc[col];
        const float cbc = sc[96 + col];
        float colsum = 0.f;
#pragma unroll
        for (int rr = 0; rr < 4; ++rr) {
            const float val = acc[f][rr] * rstd_r[rr] - mur_r[rr] * swc + cbc;
            outb[(size_t)(orow0 + rr) * MID_ + col] = (__bf16)val;
            colsum += val;
        }
        if (half == 0) {
            colsum += __shfl_xor(colsum, 16, 64);
            colsum += __shfl_xor(colsum, 32, 64);
            if (l4 == 0) atomicAdd(&part[batch * MID_ + col], colsum);
        }
    }
}

// ---------------------------------------------------------------------------
// K_mlpdyn: fused MLP+softmax (per-block recompute) + dyn build (r17).
// ---------------------------------------------------------------------------
__global__ __launch_bounds__(256) void k_mlpdyn(const float* __restrict__ part,
        const float* __restrict__ m1w, const float* __restrict__ m1b,
        const float* __restrict__ m2w, const float* __restrict__ m2b,
        const float* __restrict__ basis, float* __restrict__ dyng) {
    const int gidx = blockIdx.x * 256 + threadIdx.x;
    const int b = gidx / 4704;
    if (b >= 8) return;
    __shared__ float gv[96];
    __shared__ float hid[24];
    __shared__ float wls[4];
    const int t = threadIdx.x;
    const int b0 = (blockIdx.x * 256) / 4704;
    const int b1 = (blockIdx.x * 256 + 255) / 4704;
    __shared__ float wts2[2][4];
    for (int bi = 0; bi <= (b1 > b0 && b1 < 8 ? 1 : 0); ++bi) {
        const int bb = bi ? b1 : b0;
        if (t < 96) gv[t] = part[bb * MID_ + t] * (1.f / 4096.f);
        __syncthreads();
        if (t < 24) {
            float s = m1b[t];
            for (int c = 0; c < 96; ++c) s += gv[c] * m1w[t * 96 + c];
            hid[t] = fmaxf(s, 0.f);
        }
        __syncthreads();
        if (t < 4) {
            float s = m2b[t];
            for (int j = 0; j < 24; ++j) s += hid[j] * m2w[t * 24 + j];
            wls[t] = s;
        }
        __syncthreads();
        if (t < 4) {
            const float m = fmaxf(fmaxf(wls[0], wls[1]), fmaxf(wls[2], wls[3]));
            const float e = __expf(wls[t] - m);
            const float sum = __expf(wls[0] - m) + __expf(wls[1] - m) +
                              __expf(wls[2] - m) + __expf(wls[3] - m);
            wts2[bi][t] = e / sum;
        }
        __syncthreads();
    }
    const int rem = gidx - b * 4704;     // pq*96 + c
    const int pq = rem / 96;
    const int c = rem - pq * 96;
    const size_t off = (size_t)c * 49 + pq;
    const float* w = wts2[(b == b0) ? 0 : 1];
    dyng[gidx] = w[0] * basis[off] + w[1] * basis[off + 4704] +
                 w[2] * basis[off + 9408] + w[3] * basis[off + 14112];
}

// ---------------------------------------------------------------------------
// K_dwstyle: FUSED depthwise-3x3+SiLU -> style GEMM -> modulation.
// Block = one (b,h) line of 64 pixels. Stage 3-line halo of temb in LDS,
// compute dwconv+SiLU into registers, write As; stage pw_w Bs OVER the halo
// (union, all halo reads complete at barrier); GEMM 64x192x96 + modulation.
// Saves the 25 MB ybuf round-trip and one launch. LDS ~52 KB -> 3 blocks/CU.
// ---------------------------------------------------------------------------
__global__ __launch_bounds__(256) void k_dwstyle(
        const __bf16* __restrict__ temb, const float* __restrict__ dww,
        const float* __restrict__ dwb, const __bf16* __restrict__ wpw,
        const float* __restrict__ pwb, const __bf16* __restrict__ xemb,
        __bf16* __restrict__ common) {
    __shared__ char smem[53248];
    // region 1 (0..39936): union { Hs[3][6144] bf16 (36864B) | Bs[192][13] bf16x8 }
    __bf16* Hs = reinterpret_cast<__bf16*>(smem);
    bf16x8 (*Bs)[13] = reinterpret_cast<bf16x8 (*)[13]>(smem);
    // region 2 (39936..53248): union { As[64][13] bf16x8 | {wdw[864], bdw[96]} }
    bf16x8 (*As)[13] = reinterpret_cast<bf16x8 (*)[13]>(smem + 39936);
    float* wdw = reinterpret_cast<float*>(smem + 39936);
    float* bdw = wdw + 864;

    const int t = threadIdx.x;
    const int b = blockIdx.x >> 6, h = blockIdx.x & 63;
    const __bf16* base = temb + (size_t)b * 4096 * MID_;

    // phase 0: stage halo (zero-padded) + dw weights (into As region)
    for (int i = t; i < 2304; i += 256) {       // 3*64*96/8 items
        const int dh = i / 768;
        const int rem = i - dh * 768;           // (w*96+c)/8
        const int hh = h + dh - 1;
        bf16x8 v = {};
        if (hh >= 0 && hh <= 63)
            v = *reinterpret_cast<const bf16x8*>(
                base + (size_t)hh * 64 * MID_ + rem * 8);
        *reinterpret_cast<bf16x8*>(&Hs[dh * 6144 + rem * 8]) = v;
    }
    for (int i = t; i < 864; i += 256) wdw[i] = dww[i];
    if (t < 96) bdw[t] = dwb[t];
    __syncthreads();

    // phase 1: dwconv + SiLU into registers (24 (w,c) pairs/thread)
    float accv[24];
#pragma unroll
    for (int i = 0; i < 24; ++i) {
        const int o = t + i * 256;
        const int w = o / 96, c = o - w * 96;
        float acc = bdw[c];
#pragma unroll
        for (int dh = 0; dh < 3; ++dh) {
            const int hh = h + dh - 1;
            if (hh < 0 || hh > 63) continue;
#pragma unroll
            for (int dw = 0; dw < 3; ++dw) {
                const int ww = w + dw - 1;
                if (ww < 0 || ww > 63) continue;
                acc += (float)Hs[dh * 6144 + ww * 96 + c] * wdw[c * 9 + dh * 3 + dw];
            }
        }
        accv[i] = acc / (1.f + __expf(-acc));
    }
    __syncthreads();   // all Hs/wdw reads done; safe to overwrite both regions

    // phase 2: write As + stage Bs (over halo region)
#pragma unroll
    for (int i = 0; i < 24; ++i) {
        const int o = t + i * 256;
        const int w = o / 96, c = o - w * 96;
        reinterpret_cast<__bf16*>(&As[w][0])[c] = (__bf16)accv[i];
    }
    for (int idx = t; idx < 2304; idx += 256) {   // 192*12
        const int rr = idx / 12, q = idx - rr * 12;
        Bs[rr][q] = *reinterpret_cast<const bf16x8*>(
            wpw + (size_t)rr * MID_ + q * 8);
    }
    __syncthreads();

    // phase 3: GEMM 64x192x96 + modulation epilogue (k_style verbatim)
    const int lane = t & 63, wave = t >> 6;
    const int l15 = lane & 15, l4 = lane >> 4;
    f32x4 acc[12] = {};
    const int ar = wave * 16 + l15;
#pragma unroll
    for (int kt = 0; kt < 3; ++kt) {
        bf16x8 a = As[ar][kt * 4 + l4];
#pragma unroll
        for (int f = 0; f < 12; ++f) {
            bf16x8 bb = Bs[f * 16 + l15][kt * 4 + l4];
            acc[f] = __builtin_amdgcn_mfma_f32_16x16x32_bf16(a, bb, acc[f], 0, 0, 0);
        }
    }
    const int row0 = blockIdx.x * 64;
    const int orow = row0 + wave * 16 + l4 * 4;
#pragma unroll
    for (int f = 0; f < 6; ++f) {
        const int col = f * 16 + l15;
        const float pbg = pwb[col];
        const float pbb = pwb[col + 96];
#pragma unroll
        for (int rr = 0; rr < 4; ++rr) {
            const float g = acc[f][rr] + pbg;
            const float bt = acc[f + 6][rr] + pbb;
            const float xe = (float)xemb[(size_t)(orow + rr) * MID_ + col];
            common[(size_t)(orow + rr) * MID_ + col] = (__bf16)(xe * (1.f + g) + bt);
        }
    }
}

// ---------------------------------------------------------------------------
// K_circ: circular 7x7 conv. dyn from dyng; guard-free sliding window.
// ---------------------------------------------------------------------------
__global__ __launch_bounds__(192) void k_circ(const __bf16* __restrict__ common,
        const float* __restrict__ dyng, __bf16* __restrict__ outc) {
    __shared__ float dyn[49 * 96];
    const int t = threadIdx.x;
    const int b = blockIdx.x >> 7;
    const int h = (blockIdx.x >> 1) & 63;
    const int wslice = blockIdx.x & 1;
    const float* dsrc = dyng + (size_t)b * 4704;
    for (int idx = t; idx < 4704; idx += 192) dyn[idx] = dsrc[idx];
    __syncthreads();
    const int c = t % 96;
    const int wg = t / 96;
    const int wbase = wslice * 32 + wg * 16;
    const __bf16* cb = common + (size_t)b * 4096 * MID_ + c;
    float acc[16] = {};
#pragma unroll 1
    for (int p = 0; p < 7; ++p) {
        const int hh = (h + 3 - p) & 63;
        const __bf16* rp = cb + (size_t)hh * 64 * MID_;
        float dynr[7];
#pragma unroll
        for (int q = 0; q < 7; ++q) dynr[q] = dyn[(p * 7 + q) * 96 + c];
        float win[22];
#pragma unroll
        for (int i = 0; i < 22; ++i)
            win[i] = (float)rp[(size_t)((wbase - 3 + i) & 63) * MID_];
#pragma unroll
        for (int li = 0; li < 16; ++li) {
            float a = acc[li];
#pragma unroll
            for (int q = 0; q < 7; ++q) a += dynr[q] * win[li + 6 - q];
            acc[li] = a;
        }
    }
    const size_t obase = ((size_t)(b * 64 + h) * 64 + wbase) * MID_ + c;
#pragma unroll
    for (int li = 0; li < 16; ++li)
        outc[obase + (size_t)li * MID_] = (__bf16)acc[li];
}

// ---------------------------------------------------------------------------
// K_up: out = a_in[32768,96] @ up_w_bf16[768,96]^T + up_b + x  (fp32 out)
// ---------------------------------------------------------------------------
__global__ __launch_bounds__(256) void k_up(const __bf16* __restrict__ a_in,
        const __bf16* __restrict__ wbf, const float* __restrict__ upb,
        const float* __restrict__ x, float* __restrict__ out) {
    __shared__ bf16x8 As[128][13];
    __shared__ bf16x8 Ws[96][13];
    const int t = threadIdx.x;
    const int mt = blockIdx.x >> 3, nt = blockIdx.x & 7;
    const int row0 = mt * 128, col0 = nt * 96;
    for (int idx = t; idx < 1536; idx += 256) {
        const int rr = idx / 12, q = idx - rr * 12;
        As[rr][q] = *reinterpret_cast<const bf16x8*>(
            a_in + (size_t)(row0 + rr) * MID_ + q * 8);
    }
    for (int idx = t; idx < 1152; idx += 256) {
        const int rr = idx / 12, q = idx - rr * 12;
        Ws[rr][q] = *reinterpret_cast<const bf16x8*>(
            wbf + (size_t)(col0 + rr) * MID_ + q * 8);
    }
    __syncthreads();
    const int lane = t & 63, wave = t >> 6;
    const int l15 = lane & 15, l4 = lane >> 4;
    f32x4 acc[2][6] = {};
#pragma unroll
    for (int kt = 0; kt < 3; ++kt) {
        bf16x8 a0 = As[wave * 32 + l15][kt * 4 + l4];
        bf16x8 a1 = As[wave * 32 + 16 + l15][kt * 4 + l4];
#pragma unroll
        for (int f = 0; f < 6; ++f) {
            bf16x8 b = Ws[f * 16 + l15][kt * 4 + l4];
            acc[0][f] = __builtin_amdgcn_mfma_f32_16x16x32_bf16(a0, b, acc[0][f], 0, 0, 0);
            acc[1][f] = __builtin_amdgcn_mfma_f32_16x16x32_bf16(a1, b, acc[1][f], 0, 0, 0);
        }
    }
#pragma unroll
    for (int mr = 0; mr < 2; ++mr) {
        const int orow = row0 + wave * 32 + mr * 16 + l4 * 4;
#pragma unroll
        for (int f = 0; f < 6; ++f) {
            const int col = col0 + f * 16 + l15;
            const float ub = upb[col];
#pragma unroll
            for (int rr = 0; rr < 4; ++rr) {
                const size_t idx = (size_t)(orow + rr) * DIM_ + col;
                out[idx] = acc[mr][f][rr] + ub + x[idx];
            }
        }
    }
}

// ---------------------------------------------------------------------------
extern "C" void kernel_launch(void* const* d_in, const int* in_sizes, int n_in,
                              void* d_out, int out_size, void* d_ws, size_t ws_size,
                              hipStream_t stream) {
    (void)in_sizes; (void)n_in; (void)out_size; (void)ws_size;
    const float* x      = (const float*)d_in[0];
    const float* tt     = (const float*)d_in[1];
    const float* ln_w   = (const float*)d_in[2];
    const float* ln_b   = (const float*)d_in[3];
    const float* down_w = (const float*)d_in[4];
    const float* down_b = (const float*)d_in[5];
    const float* ln1_w  = (const float*)d_in[6];
    const float* ln1_b  = (const float*)d_in[7];
    const float* down1_w= (const float*)d_in[8];
    const float* down1_b= (const float*)d_in[9];
    const float* dw_w   = (const float*)d_in[10];
    const float* dw_b   = (const float*)d_in[11];
    const float* pw_w   = (const float*)d_in[12];
    const float* pw_b   = (const float*)d_in[13];
    const float* m1w    = (const float*)d_in[14];
    const float* m1b    = (const float*)d_in[15];
    const float* m2w    = (const float*)d_in[16];
    const float* m2b    = (const float*)d_in[17];
    const float* basis  = (const float*)d_in[18];
    const float* up_w   = (const float*)d_in[19];
    const float* up_b   = (const float*)d_in[20];
    float* out = (float*)d_out;
    char* ws = (char*)d_ws;

    // workspace layout (bytes)
    __bf16* wln_down  = (__bf16*)(ws + 0);          // 96*768*2  = 147456
    __bf16* wln_down1 = (__bf16*)(ws + 147456);
    __bf16* wbf_up    = (__bf16*)(ws + 294912);     // 768*96*2
    __bf16* wbf_pw    = (__bf16*)(ws + 442368);     // 192*96*2 = 36864
    float*  part      = (float*)(ws + 479232);      // 8*96*4 = 3072
    float*  swcb      = (float*)(ws + 482560);      // 2*192*4 = 1536
    __bf16* x_emb     = (__bf16*)(ws + 524288);     // 32768*96*2 = 6291456
    __bf16* t_emb     = (__bf16*)(ws + 6815744);
    __bf16* common    = (__bf16*)(ws + 19398656);
    __bf16* convout   = (__bf16*)(ws + 25690112);
    float*  dyng      = (float*)(ws + 31981568);    // 8*49*96*4 = 150528

    // opt-in to >64KB dynamic LDS for k_downf (not a stream op; capture-safe)
    (void)hipFuncSetAttribute((const void*)k_downf,
                              hipFuncAttributeMaxDynamicSharedMemorySize, 147456);

    k_prep<<<141, 256, 0, stream>>>(down_w, down_b, ln_w, ln_b,
                                    down1_w, down1_b, ln1_w, ln1_b,
                                    wln_down, wln_down1, swcb,
                                    up_w, pw_w, wbf_up, wbf_pw, part);
    k_downf<<<256, 1024, 147456, stream>>>(x, tt, wln_down, wln_down1, swcb,
                                           x_emb, t_emb, part);
    k_mlpdyn<<<148, 256, 0, stream>>>(part, m1w, m1b, m2w, m2b, basis, dyng);
    k_dwstyle<<<512, 256, 0, stream>>>(t_emb, dw_w, dw_b, wbf_pw, pw_b,
                                       x_emb, common);
    k_circ<<<1024, 192, 0, stream>>>(common, dyng, convout);
    k_up<<<2048, 256, 0, stream>>>(convout, wbf_up, up_b, x, out);
}